// Round 8
// baseline (139.415 us; speedup 1.0000x reference)
//
#include <hip/hip_runtime.h>
#include <math.h>

// Problem constants
#define B_  4
#define T_  2048
#define C_  1024
#define HS_ 64
#define M_  (B_*T_)   // 8192 rows
#define NCAT 192
#define SCALE_ 0.03125f   // C^-0.5

typedef unsigned short ushort_t;
typedef short bf16x8 __attribute__((ext_vector_type(8)));
typedef float f32x4 __attribute__((ext_vector_type(4)));

static __device__ __forceinline__ unsigned short f2bf(float f) {   // RNE (for inputs)
    union { float f; unsigned int u; } c; c.f = f;
    unsigned int u = c.u;
    return (unsigned short)((u + 0x7FFFu + ((u >> 16) & 1u)) >> 16);
}
static __device__ __forceinline__ unsigned short f2bf_fast(float f) { // 2-op round
    union { float f; unsigned int u; } c; c.f = f;
    return (unsigned short)((c.u + 0x8000u) >> 16);
}
static __device__ __forceinline__ float b2f(unsigned short u) {
    union { unsigned int u; float f; } c; c.u = ((unsigned int)u) << 16;
    return c.f;
}

// ---------------------------------------------------------------------------
// Kernel 1: W -> wt bf16 transposed [192][1024] (4/thread, 192 blocks).
// ---------------------------------------------------------------------------
__global__ void wconv_kernel(const float* __restrict__ Wq, const float* __restrict__ Wk,
                             const float* __restrict__ Wv, ushort_t* __restrict__ wt) {
    int idx = (blockIdx.x * 256 + threadIdx.x) * 4;   // < 192*1024
    int n = idx >> 10;
    int k0 = idx & 1023;
    const float* W = (n < 64) ? Wq : (n < 128) ? Wk : Wv;
    int nn = n & 63;
    ushort_t o0 = f2bf(W[(k0 + 0) * HS_ + nn]);
    ushort_t o1 = f2bf(W[(k0 + 1) * HS_ + nn]);
    ushort_t o2 = f2bf(W[(k0 + 2) * HS_ + nn]);
    ushort_t o3 = f2bf(W[(k0 + 3) * HS_ + nn]);
    uint2 d;
    d.x = (unsigned)o0 | ((unsigned)o1 << 16);
    d.y = (unsigned)o2 | ((unsigned)o3 << 16);
    *(uint2*)(wt + (size_t)n * C_ + k0) = d;
}

// ---------------------------------------------------------------------------
// Kernel 2: QKV projection, K-split x8 across a 512-thread block + LDS reduce.
// Wave = 16 rows x 64 cols x K-slice(128) = 4-iter chain, SW-pipelined:
// next iter's loads issue right after current data is consumed.
// grid (512 rowgroups, 3 outputs{Q,K,V}). Q pre-scaled. V transposed [b][d][t].
// ---------------------------------------------------------------------------
__global__ __launch_bounds__(512, 6) void proj_kernel(const float* __restrict__ x,
    const ushort_t* __restrict__ wt,
    ushort_t* __restrict__ qws, ushort_t* __restrict__ kws, ushort_t* __restrict__ vt) {
    __shared__ __align__(16) f32x4 red[7][4][64];   // 28 KB: waves 1-7 partials

    int tid  = threadIdx.x;
    int wid  = tid >> 6;       // K-slice 0..7
    int lane = tid & 63;
    int qd   = lane >> 4;
    int lq   = lane & 15;
    int r0   = blockIdx.x * 16;    // 512 rowgroups of 16
    int cg   = blockIdx.y;         // 0=Q 1=K 2=V (64 cols each)

    f32x4 acc[4];
    #pragma unroll
    for (int i = 0; i < 4; i++) acc[i] = (f32x4){0.f,0.f,0.f,0.f};

    const float*    xp = x  + (size_t)(r0 + lq) * C_ + wid * 128 + qd * 8;
    const ushort_t* wp = wt + (size_t)(cg * 64 + lq) * C_ + wid * 128 + qd * 8;

    // prologue loads (k-offset 0 of this wave's slice)
    float4 a0 = *(const float4*)(xp);
    float4 a1 = *(const float4*)(xp + 4);
    bf16x8 w0 = *(const bf16x8*)(wp);
    bf16x8 w1 = *(const bf16x8*)(wp + (size_t)16 * C_);
    bf16x8 w2 = *(const bf16x8*)(wp + (size_t)32 * C_);
    bf16x8 w3 = *(const bf16x8*)(wp + (size_t)48 * C_);

    #pragma unroll
    for (int i = 0; i < 4; i++) {
        union { bf16x8 v; ushort_t u[8]; } af;
        af.u[0] = f2bf(a0.x); af.u[1] = f2bf(a0.y); af.u[2] = f2bf(a0.z); af.u[3] = f2bf(a0.w);
        af.u[4] = f2bf(a1.x); af.u[5] = f2bf(a1.y); af.u[6] = f2bf(a1.z); af.u[7] = f2bf(a1.w);
        if (i < 3) {   // a consumed by cvt -> refill for next iter
            a0 = *(const float4*)(xp + 32 * (i + 1));
            a1 = *(const float4*)(xp + 32 * (i + 1) + 4);
        }
        acc[0] = __builtin_amdgcn_mfma_f32_16x16x32_bf16(af.v, w0, acc[0], 0, 0, 0);
        acc[1] = __builtin_amdgcn_mfma_f32_16x16x32_bf16(af.v, w1, acc[1], 0, 0, 0);
        acc[2] = __builtin_amdgcn_mfma_f32_16x16x32_bf16(af.v, w2, acc[2], 0, 0, 0);
        acc[3] = __builtin_amdgcn_mfma_f32_16x16x32_bf16(af.v, w3, acc[3], 0, 0, 0);
        if (i < 3) {   // w consumed by MFMAs -> refill for next iter
            w0 = *(const bf16x8*)(wp + 32 * (i + 1));
            w1 = *(const bf16x8*)(wp + (size_t)16 * C_ + 32 * (i + 1));
            w2 = *(const bf16x8*)(wp + (size_t)32 * C_ + 32 * (i + 1));
            w3 = *(const bf16x8*)(wp + (size_t)48 * C_ + 32 * (i + 1));
        }
    }

    if (wid) {
        #pragma unroll
        for (int nt = 0; nt < 4; nt++) red[wid - 1][nt][lane] = acc[nt];
    }
    __syncthreads();
    if (wid == 0) {
        #pragma unroll
        for (int nt = 0; nt < 4; nt++) {
            f32x4 a = acc[nt];
            #pragma unroll
            for (int w = 0; w < 7; w++) {
                f32x4 p = red[w][nt][lane];
                a[0] += p[0]; a[1] += p[1]; a[2] += p[2]; a[3] += p[3];
            }
            int col = nt * 16 + lq;   // 0..63 within this output
            #pragma unroll
            for (int r = 0; r < 4; r++) {
                int row = r0 + qd * 4 + r;
                float v = a[r];
                if (cg == 0) v *= SCALE_;           // pre-scale Q
                ushort_t val = f2bf(v);
                if (cg == 0)      qws[(size_t)row * HS_ + col] = val;
                else if (cg == 1) kws[(size_t)row * HS_ + col] = val;
                else {
                    int b = row >> 11, t = row & 2047;
                    vt[((size_t)b * 64 + col) * T_ + t] = val;
                }
            }
        }
    }
}

// ---------------------------------------------------------------------------
// Kernel 3: causal flash, transposed-S, no online max, KW=4 chunks,
// SW-pipelined: kf reloads right after S-MFMAs, vf right after PV-MFMAs.
// grid (544 pairs, 4 batches), block = 2 waves = 32 q-rows.
// ---------------------------------------------------------------------------
#define KW 4
__global__ __launch_bounds__(128) void flash_kernel(const ushort_t* __restrict__ qws,
    const ushort_t* __restrict__ kws, const ushort_t* __restrict__ vt,
    ushort_t* __restrict__ opart, float* __restrict__ lpart) {
    __shared__ __align__(16) ushort_t Pw[2][16 * 40];

    int tid  = threadIdx.x;
    int wid  = tid >> 6;
    int lane = tid & 63;
    int qd   = lane >> 4;
    int lq   = lane & 15;

    int batch = blockIdx.y;
    int idx   = blockIdx.x;
    // tiles 4g..4g+3 each have g+1 chunks; cumulative before group g = 2g(g+1)
    int g = (int)((sqrtf(2.f * idx + 1.f) - 1.f) * 0.5f);
    while (2 * (g + 1) * (g + 2) <= idx) g++;
    while (2 * g * (g + 1) > idx) g--;
    int rem  = idx - 2 * g * (g + 1);
    int tile = 4 * g + rem / (g + 1);
    int c    = rem % (g + 1);

    int q0   = tile * 32;
    int qrow = q0 + wid * 16 + lq;
    int grow = batch * T_ + qrow;

    bf16x8 qf[2];
    #pragma unroll
    for (int st = 0; st < 2; st++)
        qf[st] = *(const bf16x8*)(qws + (size_t)grow * HS_ + st * 32 + qd * 8);

    float lsum = 0.f;
    f32x4 O[4];
    #pragma unroll
    for (int nt = 0; nt < 4; nt++) O[nt] = (f32x4){0.f,0.f,0.f,0.f};

    int kt0 = c * KW;
    int kt_end = c * KW + KW; if (kt_end > tile + 1) kt_end = tile + 1;

    ushort_t* pw = &Pw[wid][lq * 40];
    const ushort_t* vbase = vt + (size_t)batch * 64 * T_;

    // prologue loads for kt0
    bf16x8 kf[4], vf[4];
    {
        int keybase = batch * T_ + kt0 * 32;
        #pragma unroll
        for (int sub = 0; sub < 2; sub++)
            #pragma unroll
            for (int st = 0; st < 2; st++)
                kf[sub * 2 + st] = *(const bf16x8*)(kws + (size_t)(keybase + sub * 16 + lq) * HS_ + st * 32 + qd * 8);
        #pragma unroll
        for (int nt = 0; nt < 4; nt++)
            vf[nt] = *(const bf16x8*)(vbase + ((size_t)nt * 16 + lq) * T_ + kt0 * 32 + qd * 8);
    }

    for (int kt = kt0; kt < kt_end; kt++) {
        bool more = (kt + 1) < kt_end;   // wave-uniform

        // S^T = K . Q^T (Q pre-scaled)
        f32x4 S[2];
        #pragma unroll
        for (int sub = 0; sub < 2; sub++) {
            f32x4 s = (f32x4){0.f,0.f,0.f,0.f};
            #pragma unroll
            for (int st = 0; st < 2; st++)
                s = __builtin_amdgcn_mfma_f32_16x16x32_bf16(kf[sub * 2 + st], qf[st], s, 0, 0, 0);
            S[sub] = s;
        }

        // kf consumed -> prefetch next key-tile's K
        if (more) {
            int kb2 = batch * T_ + (kt + 1) * 32;
            #pragma unroll
            for (int sub = 0; sub < 2; sub++)
                #pragma unroll
                for (int st = 0; st < 2; st++)
                    kf[sub * 2 + st] = *(const bf16x8*)(kws + (size_t)(kb2 + sub * 16 + lq) * HS_ + st * 32 + qd * 8);
        }

        // P = exp(S) (no max subtraction); mask only on the diagonal tile
        if (kt == tile) {
            #pragma unroll
            for (int sub = 0; sub < 2; sub++)
                #pragma unroll
                for (int r = 0; r < 4; r++) {
                    int key = kt * 32 + sub * 16 + qd * 4 + r;
                    float p = (key <= qrow) ? __expf(S[sub][r]) : 0.f;
                    S[sub][r] = p;
                    lsum += p;
                }
        } else {
            #pragma unroll
            for (int sub = 0; sub < 2; sub++)
                #pragma unroll
                for (int r = 0; r < 4; r++) {
                    float p = __expf(S[sub][r]);
                    S[sub][r] = p;
                    lsum += p;
                }
        }

        // P^T: C-layout -> LDS (b64 writes) -> B-layout (b128 read), per-wave
        #pragma unroll
        for (int sub = 0; sub < 2; sub++) {
            uint2 d;
            d.x = (unsigned)f2bf_fast(S[sub][0]) | ((unsigned)f2bf_fast(S[sub][1]) << 16);
            d.y = (unsigned)f2bf_fast(S[sub][2]) | ((unsigned)f2bf_fast(S[sub][3]) << 16);
            *(uint2*)(pw + sub * 16 + qd * 4) = d;
        }
        bf16x8 pf = *(const bf16x8*)(pw + qd * 8);

        // O^T += V^T . P^T
        #pragma unroll
        for (int nt = 0; nt < 4; nt++)
            O[nt] = __builtin_amdgcn_mfma_f32_16x16x32_bf16(vf[nt], pf, O[nt], 0, 0, 0);

        // vf consumed -> prefetch next key-tile's V
        if (more) {
            #pragma unroll
            for (int nt = 0; nt < 4; nt++)
                vf[nt] = *(const bf16x8*)(vbase + ((size_t)nt * 16 + lq) * T_ + (kt + 1) * 32 + qd * 8);
        }
    }

    // deferred cross-quad l reduction (linear — no rescaling existed)
    lsum += __shfl_xor(lsum, 16, 64);
    lsum += __shfl_xor(lsum, 32, 64);

    #pragma unroll
    for (int nt = 0; nt < 4; nt++) {
        uint2 d;
        d.x = (unsigned)f2bf_fast(O[nt][0]) | ((unsigned)f2bf_fast(O[nt][1]) << 16);
        d.y = (unsigned)f2bf_fast(O[nt][2]) | ((unsigned)f2bf_fast(O[nt][3]) << 16);
        *(uint2*)(opart + ((size_t)c * M_ + grow) * HS_ + nt * 16 + qd * 4) = d;
    }
    if (qd == 0) lpart[(size_t)c * M_ + grow] = lsum;
}

// ---------------------------------------------------------------------------
// Kernel 4: combine chunks: out = sum_c O_c / sum_c l_c. 16 threads/row.
// ---------------------------------------------------------------------------
__global__ void combine_kernel(const ushort_t* __restrict__ opart,
    const float* __restrict__ lpart, float* __restrict__ out) {
    int idx = blockIdx.x * 256 + threadIdx.x;   // < 8192*16
    int row = idx >> 4;
    int d   = (idx & 15) << 2;
    int nc  = ((row & 2047) >> 7) + 1;   // tile/4 + 1 chunks

    float L = 0.f;
    float4 acc = make_float4(0.f, 0.f, 0.f, 0.f);
    for (int c = 0; c < nc; c++) {
        L += lpart[(size_t)c * M_ + row];
        const ushort_t* op = opart + ((size_t)c * M_ + row) * HS_ + d;
        ushort2 a = *(const ushort2*)op;
        ushort2 b = *(const ushort2*)(op + 2);
        acc.x += b2f(a.x); acc.y += b2f(a.y);
        acc.z += b2f(b.x); acc.w += b2f(b.y);
    }
    float li = 1.f / L;
    *(float4*)(out + (size_t)row * HS_ + d) =
        make_float4(acc.x * li, acc.y * li, acc.z * li, acc.w * li);
}

// ---------------------------------------------------------------------------
extern "C" void kernel_launch(void* const* d_in, const int* in_sizes, int n_in,
                              void* d_out, int out_size, void* d_ws, size_t ws_size,
                              hipStream_t stream) {
    const float* x  = (const float*)d_in[0];
    const float* Wq = (const float*)d_in[1];
    const float* Wk = (const float*)d_in[2];
    const float* Wv = (const float*)d_in[3];
    float* out = (float*)d_out;

    ushort_t* wt  = (ushort_t*)d_ws;                    // 192*1024
    ushort_t* qws = wt  + (size_t)NCAT * C_;            // 8192*64
    ushort_t* kws = qws + (size_t)M_ * HS_;
    ushort_t* vt  = kws + (size_t)M_ * HS_;
    float* lpart  = (float*)(vt + (size_t)M_ * HS_);    // 16*8192 fp32
    ushort_t* opart = (ushort_t*)(lpart + (size_t)16 * M_);  // 16*8192*64 bf16

    wconv_kernel<<<NCAT * C_ / (256 * 4), 256, 0, stream>>>(Wq, Wk, Wv, wt);
    proj_kernel<<<dim3(512, 3), 512, 0, stream>>>(x, wt, qws, kws, vt);
    flash_kernel<<<dim3(544, 4), 128, 0, stream>>>(qws, kws, vt, opart, lpart);
    combine_kernel<<<M_ * 16 / 256, 256, 0, stream>>>(opart, lpart, out);
}

// Round 9
// 131.044 us; speedup vs baseline: 1.0639x; 1.0639x over previous
//
#include <hip/hip_runtime.h>
#include <math.h>

// Problem constants
#define B_  4
#define T_  2048
#define C_  1024
#define HS_ 64
#define M_  (B_*T_)   // 8192 rows
#define NCAT 192
#define SCALE_ 0.03125f   // C^-0.5

typedef unsigned short ushort_t;
typedef short bf16x8 __attribute__((ext_vector_type(8)));
typedef float f32x4 __attribute__((ext_vector_type(4)));

static __device__ __forceinline__ unsigned short f2bf(float f) {   // RNE (for inputs)
    union { float f; unsigned int u; } c; c.f = f;
    unsigned int u = c.u;
    return (unsigned short)((u + 0x7FFFu + ((u >> 16) & 1u)) >> 16);
}
static __device__ __forceinline__ unsigned short f2bf_fast(float f) { // 2-op round
    union { float f; unsigned int u; } c; c.f = f;
    return (unsigned short)((c.u + 0x8000u) >> 16);
}
static __device__ __forceinline__ float b2f(unsigned short u) {
    union { unsigned int u; float f; } c; c.u = ((unsigned int)u) << 16;
    return c.f;
}

// ---------------------------------------------------------------------------
// Kernel 1: W -> wt bf16 transposed [192][1024] (4/thread, 192 blocks).
// ---------------------------------------------------------------------------
__global__ void wconv_kernel(const float* __restrict__ Wq, const float* __restrict__ Wk,
                             const float* __restrict__ Wv, ushort_t* __restrict__ wt) {
    int idx = (blockIdx.x * 256 + threadIdx.x) * 4;   // < 192*1024
    int n = idx >> 10;
    int k0 = idx & 1023;
    const float* W = (n < 64) ? Wq : (n < 128) ? Wk : Wv;
    int nn = n & 63;
    ushort_t o0 = f2bf(W[(k0 + 0) * HS_ + nn]);
    ushort_t o1 = f2bf(W[(k0 + 1) * HS_ + nn]);
    ushort_t o2 = f2bf(W[(k0 + 2) * HS_ + nn]);
    ushort_t o3 = f2bf(W[(k0 + 3) * HS_ + nn]);
    uint2 d;
    d.x = (unsigned)o0 | ((unsigned)o1 << 16);
    d.y = (unsigned)o2 | ((unsigned)o3 << 16);
    *(uint2*)(wt + (size_t)n * C_ + k0) = d;
}

// ---------------------------------------------------------------------------
// Kernel 2: QKV projection, ONE PASS over x. Block = 512 thr = 8 waves =
// 8 K-slices of 128; wave = 16 rows x ALL 192 cols (12 MFMA tiles).
// 14 independent loads/iter in flight. 3-round LDS tree reduce (49 KB).
// grid 512 blocks (2/CU). Q pre-scaled. V transposed [b][d][t].
// ---------------------------------------------------------------------------
__global__ __launch_bounds__(512, 4) void proj_kernel(const float* __restrict__ x,
    const ushort_t* __restrict__ wt,
    ushort_t* __restrict__ qws, ushort_t* __restrict__ kws, ushort_t* __restrict__ vt) {
    __shared__ __align__(16) f32x4 red[4][12 * 64];   // 49 KB

    int tid  = threadIdx.x;
    int wid  = tid >> 6;       // K-slice 0..7
    int lane = tid & 63;
    int qd   = lane >> 4;
    int lq   = lane & 15;
    int r0   = blockIdx.x * 16;    // 512 rowgroups of 16

    f32x4 acc[12];
    #pragma unroll
    for (int i = 0; i < 12; i++) acc[i] = (f32x4){0.f,0.f,0.f,0.f};

    const float*    xp = x  + (size_t)(r0 + lq) * C_ + wid * 128 + qd * 8;
    const ushort_t* wp = wt + (size_t)lq * C_ + wid * 128 + qd * 8;

    #pragma unroll
    for (int i = 0; i < 4; i++) {
        float4 a0 = *(const float4*)(xp + i * 32);
        float4 a1 = *(const float4*)(xp + i * 32 + 4);
        union { bf16x8 v; ushort_t u[8]; } af;
        af.u[0] = f2bf(a0.x); af.u[1] = f2bf(a0.y); af.u[2] = f2bf(a0.z); af.u[3] = f2bf(a0.w);
        af.u[4] = f2bf(a1.x); af.u[5] = f2bf(a1.y); af.u[6] = f2bf(a1.z); af.u[7] = f2bf(a1.w);
        #pragma unroll
        for (int nt = 0; nt < 12; nt++) {
            bf16x8 bv = *(const bf16x8*)(wp + (size_t)nt * 16 * C_ + i * 32);
            acc[nt] = __builtin_amdgcn_mfma_f32_16x16x32_bf16(af.v, bv, acc[nt], 0, 0, 0);
        }
    }

    // tree reduce 8 -> 4 -> 2 -> 1 through 4 LDS slots
    if (wid >= 4) {
        #pragma unroll
        for (int nt = 0; nt < 12; nt++) red[wid - 4][nt * 64 + lane] = acc[nt];
    }
    __syncthreads();
    if (wid < 4) {
        #pragma unroll
        for (int nt = 0; nt < 12; nt++) acc[nt] += red[wid][nt * 64 + lane];
    }
    __syncthreads();
    if (wid == 2 || wid == 3) {
        #pragma unroll
        for (int nt = 0; nt < 12; nt++) red[wid][nt * 64 + lane] = acc[nt];
    }
    __syncthreads();
    if (wid < 2) {
        #pragma unroll
        for (int nt = 0; nt < 12; nt++) acc[nt] += red[wid + 2][nt * 64 + lane];
    }
    __syncthreads();
    if (wid == 1) {
        #pragma unroll
        for (int nt = 0; nt < 12; nt++) red[0][nt * 64 + lane] = acc[nt];
    }
    __syncthreads();
    if (wid == 0) {
        #pragma unroll
        for (int nt = 0; nt < 12; nt++) {
            acc[nt] += red[0][nt * 64 + lane];
            int outn = nt >> 2;            // 0=Q 1=K 2=V
            int col  = (nt & 3) * 16 + lq; // 0..63
            #pragma unroll
            for (int r = 0; r < 4; r++) {
                int row = r0 + qd * 4 + r;
                float v = acc[nt][r];
                if (outn == 0) v *= SCALE_;           // pre-scale Q
                ushort_t val = f2bf(v);
                if (outn == 0)      qws[(size_t)row * HS_ + col] = val;
                else if (outn == 1) kws[(size_t)row * HS_ + col] = val;
                else {
                    int b = row >> 11, t = row & 2047;
                    vt[((size_t)b * 64 + col) * T_ + t] = val;
                }
            }
        }
    }
}

// ---------------------------------------------------------------------------
// Kernel 3: causal flash, transposed-S, no online max. Chunk = 128 keys,
// processed in 64-key iterations: 16 global loads batched per iter.
// grid (544 pairs, 4 batches), block = 2 waves = 32 q-rows.
// Out-of-range key loads are in-bounds (< T) and masked to zero.
// ---------------------------------------------------------------------------
__global__ __launch_bounds__(128) void flash_kernel(const ushort_t* __restrict__ qws,
    const ushort_t* __restrict__ kws, const ushort_t* __restrict__ vt,
    ushort_t* __restrict__ opart, float* __restrict__ lpart) {
    __shared__ __align__(16) ushort_t Pw[2][16 * 72];   // stride 72 bf16 = 144 B

    int tid  = threadIdx.x;
    int wid  = tid >> 6;
    int lane = tid & 63;
    int qd   = lane >> 4;
    int lq   = lane & 15;

    int batch = blockIdx.y;
    int idx   = blockIdx.x;
    // tiles 4g..4g+3 each have g+1 chunks; cumulative before group g = 2g(g+1)
    int g = (int)((sqrtf(2.f * idx + 1.f) - 1.f) * 0.5f);
    while (2 * (g + 1) * (g + 2) <= idx) g++;
    while (2 * g * (g + 1) > idx) g--;
    int rem  = idx - 2 * g * (g + 1);
    int tile = 4 * g + rem / (g + 1);
    int c    = rem % (g + 1);

    int q0   = tile * 32;
    int qrow = q0 + wid * 16 + lq;
    int grow = batch * T_ + qrow;

    bf16x8 qf[2];
    #pragma unroll
    for (int st = 0; st < 2; st++)
        qf[st] = *(const bf16x8*)(qws + (size_t)grow * HS_ + st * 32 + qd * 8);

    float lsum = 0.f;
    f32x4 O[4];
    #pragma unroll
    for (int nt = 0; nt < 4; nt++) O[nt] = (f32x4){0.f,0.f,0.f,0.f};

    int kstart = c * 128;
    int klimit = q0 + 32;                                    // exclusive valid-key bound
    int kend   = (kstart + 128 < klimit) ? kstart + 128 : klimit;

    ushort_t* pw = &Pw[wid][lq * 72];
    const ushort_t* kp = kws + (size_t)batch * T_ * HS_;
    const ushort_t* vbase = vt + (size_t)batch * 64 * T_;

    for (int kb = kstart; kb < kend; kb += 64) {
        // batched loads: 8 K-frags + 8 V-frags, all independent
        bf16x8 kf[8], vf[8];
        #pragma unroll
        for (int sub = 0; sub < 4; sub++)
            #pragma unroll
            for (int st = 0; st < 2; st++)
                kf[sub * 2 + st] = *(const bf16x8*)(kp + (size_t)(kb + sub * 16 + lq) * HS_ + st * 32 + qd * 8);
        #pragma unroll
        for (int nt = 0; nt < 4; nt++)
            #pragma unroll
            for (int kk = 0; kk < 2; kk++)
                vf[nt * 2 + kk] = *(const bf16x8*)(vbase + ((size_t)nt * 16 + lq) * T_ + kb + kk * 32 + qd * 8);

        // S^T = K . Q^T (Q pre-scaled): 4 sub-tiles of 16 keys
        f32x4 S[4];
        #pragma unroll
        for (int sub = 0; sub < 4; sub++) {
            f32x4 s = (f32x4){0.f,0.f,0.f,0.f};
            #pragma unroll
            for (int st = 0; st < 2; st++)
                s = __builtin_amdgcn_mfma_f32_16x16x32_bf16(kf[sub * 2 + st], qf[st], s, 0, 0, 0);
            S[sub] = s;
        }

        // P = exp(S); mask only when this 64-key block can cross the diagonal
        if (kb + 64 > q0) {
            #pragma unroll
            for (int sub = 0; sub < 4; sub++)
                #pragma unroll
                for (int r = 0; r < 4; r++) {
                    int key = kb + sub * 16 + qd * 4 + r;
                    float p = (key <= qrow) ? __expf(S[sub][r]) : 0.f;
                    S[sub][r] = p;
                    lsum += p;
                }
        } else {
            #pragma unroll
            for (int sub = 0; sub < 4; sub++)
                #pragma unroll
                for (int r = 0; r < 4; r++) {
                    float p = __expf(S[sub][r]);
                    S[sub][r] = p;
                    lsum += p;
                }
        }

        // P^T: C-layout -> LDS (4x b64 writes) -> B-layout (2x b128 reads)
        #pragma unroll
        for (int sub = 0; sub < 4; sub++) {
            uint2 d;
            d.x = (unsigned)f2bf_fast(S[sub][0]) | ((unsigned)f2bf_fast(S[sub][1]) << 16);
            d.y = (unsigned)f2bf_fast(S[sub][2]) | ((unsigned)f2bf_fast(S[sub][3]) << 16);
            *(uint2*)(pw + sub * 16 + qd * 4) = d;
        }
        bf16x8 pf0 = *(const bf16x8*)(pw + qd * 8);
        bf16x8 pf1 = *(const bf16x8*)(pw + 32 + qd * 8);

        // O^T += V^T . P^T (K-dim = 64 keys = 2 MFMA k-steps)
        #pragma unroll
        for (int nt = 0; nt < 4; nt++) {
            O[nt] = __builtin_amdgcn_mfma_f32_16x16x32_bf16(vf[nt * 2 + 0], pf0, O[nt], 0, 0, 0);
            O[nt] = __builtin_amdgcn_mfma_f32_16x16x32_bf16(vf[nt * 2 + 1], pf1, O[nt], 0, 0, 0);
        }
    }

    // deferred cross-quad l reduction (linear — no rescaling existed)
    lsum += __shfl_xor(lsum, 16, 64);
    lsum += __shfl_xor(lsum, 32, 64);

    #pragma unroll
    for (int nt = 0; nt < 4; nt++) {
        uint2 d;
        d.x = (unsigned)f2bf_fast(O[nt][0]) | ((unsigned)f2bf_fast(O[nt][1]) << 16);
        d.y = (unsigned)f2bf_fast(O[nt][2]) | ((unsigned)f2bf_fast(O[nt][3]) << 16);
        *(uint2*)(opart + ((size_t)c * M_ + grow) * HS_ + nt * 16 + qd * 4) = d;
    }
    if (qd == 0) lpart[(size_t)c * M_ + grow] = lsum;
}

// ---------------------------------------------------------------------------
// Kernel 4: combine chunks: out = sum_c O_c / sum_c l_c. 16 threads/row.
// ---------------------------------------------------------------------------
__global__ void combine_kernel(const ushort_t* __restrict__ opart,
    const float* __restrict__ lpart, float* __restrict__ out) {
    int idx = blockIdx.x * 256 + threadIdx.x;   // < 8192*16
    int row = idx >> 4;
    int d   = (idx & 15) << 2;
    int nc  = ((row & 2047) >> 7) + 1;   // tile/4 + 1 chunks

    float L = 0.f;
    float4 acc = make_float4(0.f, 0.f, 0.f, 0.f);
    for (int c = 0; c < nc; c++) {
        L += lpart[(size_t)c * M_ + row];
        const ushort_t* op = opart + ((size_t)c * M_ + row) * HS_ + d;
        ushort2 a = *(const ushort2*)op;
        ushort2 b = *(const ushort2*)(op + 2);
        acc.x += b2f(a.x); acc.y += b2f(a.y);
        acc.z += b2f(b.x); acc.w += b2f(b.y);
    }
    float li = 1.f / L;
    *(float4*)(out + (size_t)row * HS_ + d) =
        make_float4(acc.x * li, acc.y * li, acc.z * li, acc.w * li);
}

// ---------------------------------------------------------------------------
extern "C" void kernel_launch(void* const* d_in, const int* in_sizes, int n_in,
                              void* d_out, int out_size, void* d_ws, size_t ws_size,
                              hipStream_t stream) {
    const float* x  = (const float*)d_in[0];
    const float* Wq = (const float*)d_in[1];
    const float* Wk = (const float*)d_in[2];
    const float* Wv = (const float*)d_in[3];
    float* out = (float*)d_out;

    ushort_t* wt  = (ushort_t*)d_ws;                    // 192*1024
    ushort_t* qws = wt  + (size_t)NCAT * C_;            // 8192*64
    ushort_t* kws = qws + (size_t)M_ * HS_;
    ushort_t* vt  = kws + (size_t)M_ * HS_;
    float* lpart  = (float*)(vt + (size_t)M_ * HS_);    // 16*8192 fp32
    ushort_t* opart = (ushort_t*)(lpart + (size_t)16 * M_);  // 16*8192*64 bf16

    wconv_kernel<<<NCAT * C_ / (256 * 4), 256, 0, stream>>>(Wq, Wk, Wv, wt);
    proj_kernel<<<512, 512, 0, stream>>>(x, wt, qws, kws, vt);
    flash_kernel<<<dim3(544, 4), 128, 0, stream>>>(qws, kws, vt, opart, lpart);
    combine_kernel<<<M_ * 16 / 256, 256, 0, stream>>>(opart, lpart, out);
}